// Round 21
// baseline (152.468 us; speedup 1.0000x reference)
//
#include <hip/hip_runtime.h>
#include <math.h>

#define THREADS 256   // 4 waves/block, 32 pts/wave, 128 pts/block

typedef __attribute__((ext_vector_type(4))) float f32x4;
typedef __attribute__((ext_vector_type(4))) int   i32x4;

#define INV2PI 0.15915494309189535f
#define WS     512.0f            // L0 fp8 weight pre-scale (2^9)
#define INV_WS 0.001953125f      // 2^-9
#define SW     61440.0f          // hidden int8 weight scale (|q| <= ~125)
#define SWF    8192.0f           // Wf int8 weight scale
#define QA     127.99609375f     // activation scale = 32767/256 (pknorm hi-byte)
#define INVH   (1.0f / (SW * QA))
#define INVF   (1.0f / (SWF * QA))

// ---------------------------------------------------------------------------
// Stream: 14 chunks x 16KB = 224KB (identical to r18/r20).
//   chunk 0      : L0 fp8 (W0 256x32, xWS/2pi): 16 frags x 512B + 8KB zero
//   chunks 1..12 : W1..W3 int8, 4 chunks/layer, cc: 0=(t0-7,s0-1) 1=(t8-15,s0-1)
//                  2=(t0-7,s2-3) 3=(t8-15,s2-3). Frag = 1KB = tile(16n) x 64k.
//                  within chunk: idx = ss*8 + tl.
//   chunk 13     : Wf int8: frags 0..3 = k-steps 0..3 (rows>=4 zero), rest zero.
// sigma64: swap k bit-fields [5:4] and [3:2] — involution.
#define NCHUNK 14
#define STREAM_BYTES (NCHUNK * 16384)
#define SBIAS_BYTES 4096

__device__ __host__ __forceinline__ int sigma64(int k) {
    return (k & 0xC3) | ((k & 0x30) >> 2) | ((k & 0x0C) << 2);
}

__device__ __forceinline__ float fast_sigmoid(float x) {
    return 1.0f / (1.0f + __expf(-x));
}

// hardware sin, input in REVOLUTIONS (weights/biases pre-scaled by 1/2pi)
__device__ __forceinline__ float hw_sin(float x) {
    float r;
    asm("v_sin_f32 %0, %1" : "=v"(r) : "v"(x));
    return r;
}

// fp8 e4m3 packing (OCP on gfx950) — L0 path only
__device__ __forceinline__ unsigned pk8_lo(float a, float b) {
    return (unsigned)__builtin_amdgcn_cvt_pk_fp8_f32(a, b, 0, false);
}
__device__ __forceinline__ unsigned pk8_hi(unsigned old, float a, float b) {
    return (unsigned)__builtin_amdgcn_cvt_pk_fp8_f32(a, b, (int)old, true);
}

// int8 activation packing: pknorm (x*32767 clamp) then take high bytes
__device__ __forceinline__ unsigned pknorm(float a, float b) {
    unsigned d;
    asm("v_cvt_pknorm_i16_f32 %0, %1, %2" : "=v"(d) : "v"(a), "v"(b));
    return d;
}
__device__ __forceinline__ int hi_bytes(unsigned lo, unsigned hi) {
    return (int)__builtin_amdgcn_perm(hi, lo, 0x07050301u);
}

// ---------------- prep kernels ----------------
__device__ __forceinline__ signed char q8(float x) {
    const float c = fminf(fmaxf(x, -127.0f), 127.0f);
    return (signed char)(int)rintf(c);
}

__global__ void build_frags(const float* __restrict__ W0,
                            const float* __restrict__ W1,
                            const float* __restrict__ W2,
                            const float* __restrict__ W3,
                            const float* __restrict__ Wf,
                            unsigned char* __restrict__ stream) {
    const int gid = blockIdx.x * 256 + threadIdx.x;   // 8B slices
    if (gid >= STREAM_BYTES / 8) return;
    const int off = gid * 8;
    const int c = off >> 14;
    const int wi = off & 16383;
    unsigned char* dst = stream + off;
    unsigned char b[8];
#pragma unroll
    for (int i = 0; i < 8; ++i) b[i] = 0;

    if (c == 0) {
        if (wi < 8192) {                 // L0 fp8, K=32 layout
            const int f = wi >> 9;
            const int wf = wi & 511;
            const int l = wf >> 3;
            const int p16 = l & 15, g = l >> 4;
            const float* row = W0 + (size_t)(f * 16 + p16) * 32;
            float v[8];
#pragma unroll
            for (int i = 0; i < 8; ++i) v[i] = row[8 * g + i] * (INV2PI * WS);
            unsigned u0 = pk8_hi(pk8_lo(v[0], v[1]), v[2], v[3]);
            unsigned u1 = pk8_hi(pk8_lo(v[4], v[5]), v[6], v[7]);
#pragma unroll
            for (int i = 0; i < 4; ++i) { b[i] = (u0 >> (8 * i)) & 0xFF; b[4 + i] = (u1 >> (8 * i)) & 0xFF; }
        }
    } else if (c <= 12) {                // hidden int8
        const int t0 = c - 1;
        const int h = t0 >> 2;
        const int cc = t0 & 3;
        const int tb = (cc & 1) * 8;
        const int sbase = (cc >> 1) * 2;
        const int fragidx = wi >> 10;
        const int wf = wi & 1023;
        const int l = wf >> 4;
        const int ib = wf & 15;
        const int ss = fragidx >> 3, tl = fragidx & 7;
        const int n = (tb + tl) * 16 + (l & 15);
        const float* W = (h == 0) ? W1 : (h == 1) ? W2 : W3;
        const float* row = W + (size_t)n * 256;
#pragma unroll
        for (int i = 0; i < 8; ++i) {
            const int k = 64 * (sbase + ss) + 16 * (l >> 4) + ib + i;
            b[i] = (unsigned char)q8(row[sigma64(k)] * (INV2PI * SW));
        }
    } else {                             // chunk 13: Wf int8
        const int fragidx = wi >> 10;
        const int wf = wi & 1023;
        const int l = wf >> 4;
        const int ib = wf & 15;
        const int r = l & 15;
        if (fragidx < 4 && r < 4) {
            const int s = fragidx;
            const float* row = Wf + (size_t)r * 256;
#pragma unroll
            for (int i = 0; i < 8; ++i) {
                const int k = 64 * s + 16 * (l >> 4) + ib + i;
                b[i] = (unsigned char)q8(row[sigma64(k)] * SWF);
            }
        }
    }
    unsigned long long pk = 0;
#pragma unroll
    for (int i = 0; i < 8; ++i) pk |= (unsigned long long)b[i] << (8 * i);
    *(unsigned long long*)dst = pk;
}

__global__ void scale_biases(const float* __restrict__ b0, const float* __restrict__ b1,
                             const float* __restrict__ b2, const float* __restrict__ b3,
                             float* __restrict__ sb) {
    const int i = blockIdx.x * 256 + threadIdx.x;
    const int l = i >> 8, j = i & 255;
    if (l == 0)      sb[i] = b0[j] * (INV2PI * WS);
    else if (l == 1) sb[i] = b1[j] * INV2PI;
    else if (l == 2) sb[i] = b2[j] * INV2PI;
    else             sb[i] = b3[j] * INV2PI;
}

// vol [B][32][32768] f32 -> dst [B*32768][32] f32 (channel-last)
__global__ void vol_chlast(const float* __restrict__ vol, float* __restrict__ dst, int nvox) {
    int v = blockIdx.x * 256 + threadIdx.x;
    if (v >= nvox) return;
    const int b = v >> 15, idx = v & 32767;
    const float* s = vol + (size_t)b * 32 * 32768 + idx;
    float* d = dst + (size_t)v * 32;
#pragma unroll
    for (int c = 0; c < 32; ++c) d[c] = s[(size_t)c * 32768];
}

// ---------------- main fused kernel ----------------
#define MF8(a, b, c)  __builtin_amdgcn_mfma_f32_16x16x32_fp8_fp8((a), (b), (c), 0, 0, 0)
#define MFI8(a, b, c) __builtin_amdgcn_mfma_i32_16x16x64_i8((a), (b), (c), 0, 0, 0)

// (256,3): cap ~170 regs/wave -> 3 blocks/CU (LDS 3x48KB=144 <= 160KB),
// 3 waves/SIMD. wreg halved to 4 frags to fit (r9 lesson: (256,4)'s 64-VGPR
// cap spills catastrophically; 3-wave point was never tried).
__global__ __launch_bounds__(THREADS, 3)
void siren_pl(const float* __restrict__ points,
              const float* __restrict__ vol,
              const float* __restrict__ bfin,
              const unsigned char* __restrict__ Wstream,
              const float* __restrict__ sb,
              const float* __restrict__ volcl, int use_cl,
              float* __restrict__ out, long long total, int N) {
    __shared__ __align__(16) unsigned char ring[3 * 16384];

    const int tid = (int)threadIdx.x;
    const int w = tid >> 6;
    const int lane = tid & 63;
    const int p16 = lane & 15;
    const int g = lane >> 4;

    const long long base = (long long)blockIdx.x * 128;

    auto stage = [&](int c) {
        if (c >= NCHUNK) return;
        const unsigned char* src = Wstream + (size_t)c * 16384;
        unsigned char* dstbase = ring + (c % 3) * 16384;
#pragma unroll
        for (int q = 0; q < 4; ++q) {
            const int off = (q * 4 + w) * 1024;
            __builtin_amdgcn_global_load_lds(
                (const __attribute__((address_space(1))) unsigned int*)(src + off + lane * 16),
                (__attribute__((address_space(3))) unsigned int*)(dstbase + off),
                16, 0, 0);
        }
    };
    stage(0);
    stage(1);
    stage(2);

    // ---- sample 2 points per lane: channels 8g..8g+7, pack to fp8 (L0) ----
    long long af0[2];
    {
#pragma unroll
        for (int ptt = 0; ptt < 2; ++ptt) {
            const long long gidx = base + w * 32 + ptt * 16 + p16;
            const long long gp = gidx < total ? gidx : total - 1;
            const int bi = (int)(gp / N);
            const float* pp = points + gp * 3;
            const float sc = 1.0f / 0.6f;
            const float ix = (pp[0] * sc + 1.0f) * 16.0f - 0.5f;
            const float iy = (pp[1] * sc + 1.0f) * 16.0f - 0.5f;
            const float iz = (pp[2] * sc + 1.0f) * 16.0f - 0.5f;
            const float fx = floorf(ix), fy = floorf(iy), fz = floorf(iz);
            const float wx = ix - fx, wy = iy - fy, wz = iz - fz;
            const int x0 = (int)fminf(fmaxf(fx, 0.0f), 31.0f);
            const int x1 = (int)fminf(fmaxf(fx + 1.0f, 0.0f), 31.0f);
            const int y0 = (int)fminf(fmaxf(fy, 0.0f), 31.0f);
            const int y1 = (int)fminf(fmaxf(fy + 1.0f, 0.0f), 31.0f);
            const int z0 = (int)fminf(fmaxf(fz, 0.0f), 31.0f);
            const int z1 = (int)fminf(fmaxf(fz + 1.0f, 0.0f), 31.0f);
            const int i000 = (z0 * 32 + y0) * 32 + x0, i001 = (z0 * 32 + y0) * 32 + x1;
            const int i010 = (z0 * 32 + y1) * 32 + x0, i011 = (z0 * 32 + y1) * 32 + x1;
            const int i100 = (z1 * 32 + y0) * 32 + x0, i101 = (z1 * 32 + y0) * 32 + x1;
            const int i110 = (z1 * 32 + y1) * 32 + x0, i111 = (z1 * 32 + y1) * 32 + x1;
            const float omx = 1.0f - wx, omy = 1.0f - wy, omz = 1.0f - wz;
            const float w000 = omz * omy * omx, w001 = omz * omy * wx;
            const float w010 = omz * wy * omx,  w011 = omz * wy * wx;
            const float w100 = wz * omy * omx,  w101 = wz * omy * wx;
            const float w110 = wz * wy * omx,   w111 = wz * wy * wx;

            f32x4 a[2];
            if (use_cl) {
                const float* vb = volcl + (size_t)bi * 32768 * 32 + g * 8;
#pragma unroll
                for (int h = 0; h < 2; ++h) {
                    const float* vh = vb + h * 4;
                    a[h]  = w000 * *(const f32x4*)(vh + (size_t)i000 * 32);
                    a[h] += w001 * *(const f32x4*)(vh + (size_t)i001 * 32);
                    a[h] += w010 * *(const f32x4*)(vh + (size_t)i010 * 32);
                    a[h] += w011 * *(const f32x4*)(vh + (size_t)i011 * 32);
                    a[h] += w100 * *(const f32x4*)(vh + (size_t)i100 * 32);
                    a[h] += w101 * *(const f32x4*)(vh + (size_t)i101 * 32);
                    a[h] += w110 * *(const f32x4*)(vh + (size_t)i110 * 32);
                    a[h] += w111 * *(const f32x4*)(vh + (size_t)i111 * 32);
                }
            } else {
                const float* vb = vol + ((size_t)bi * 32 + (size_t)g * 8) * 32768;
#pragma unroll
                for (int c = 0; c < 8; ++c) {
                    const float* vc = vb + (size_t)c * 32768;
                    a[c >> 2][c & 3] =
                        vc[i000] * w000 + vc[i001] * w001 + vc[i010] * w010 + vc[i011] * w011 +
                        vc[i100] * w100 + vc[i101] * w101 + vc[i110] * w110 + vc[i111] * w111;
                }
            }
            const unsigned u0 = pk8_hi(pk8_lo(a[0][0], a[0][1]), a[0][2], a[0][3]);
            const unsigned u1 = pk8_hi(pk8_lo(a[1][0], a[1][1]), a[1][2], a[1][3]);
            af0[ptt] = (long long)(((unsigned long long)u1 << 32) | u0);
        }
    }

    f32x4 acc0A[2][8], acc0B[2][8];   // L0 f32 acc (die after first packs)
    i32x4 accA[2][8],  accB[2][8];    // hidden int32 acc
    i32x4 S0[2], S1[2], S2[2], S3[2]; // packed int8 activations, k-steps 0..3
    i32x4 wreg[4];                    // rotating weight buffer (halved: fit 3 waves/SIMD)

    auto frag_i8 = [&](int slot, int idx) -> i32x4 {
        return *(const i32x4*)&ring[slot * 16384 + idx * 1024 + lane * 16];
    };
    auto frag_f8 = [&](int idx) -> long long {
        return *(const long long*)&ring[idx * 512 + lane * 8];
    };
    auto initf = [&](f32x4 (&A)[2][8], int ntbase) {
#pragma unroll
        for (int m = 0; m < 8; ++m) {
            const f32x4 bv = *(const f32x4*)&sb[(ntbase + m) * 16 + 4 * g];
            A[0][m] = bv; A[1][m] = bv;
        }
    };
    auto zeroacc = [&](i32x4 (&A)[2][8]) {
        const i32x4 z = {0, 0, 0, 0};
#pragma unroll
        for (int m = 0; m < 8; ++m) { A[0][m] = z; A[1][m] = z; }
    };
    auto packL0 = [&](f32x4 (&A)[2][8], i32x4 (&Sa)[2], i32x4 (&Sb)[2]) {
#pragma unroll
        for (int ptt = 0; ptt < 2; ++ptt)
#pragma unroll
            for (int d = 0; d < 4; ++d) {
                float s0 = hw_sin(A[ptt][d][0] * INV_WS);
                float s1 = hw_sin(A[ptt][d][1] * INV_WS);
                float s2 = hw_sin(A[ptt][d][2] * INV_WS);
                float s3 = hw_sin(A[ptt][d][3] * INV_WS);
                Sa[ptt][d] = hi_bytes(pknorm(s0, s1), pknorm(s2, s3));
                s0 = hw_sin(A[ptt][4 + d][0] * INV_WS);
                s1 = hw_sin(A[ptt][4 + d][1] * INV_WS);
                s2 = hw_sin(A[ptt][4 + d][2] * INV_WS);
                s3 = hw_sin(A[ptt][4 + d][3] * INV_WS);
                Sb[ptt][d] = hi_bytes(pknorm(s0, s1), pknorm(s2, s3));
            }
    };
    auto packH = [&](i32x4 (&A)[2][8], const float* bp, int nb,
                     i32x4 (&Sa)[2], i32x4 (&Sb)[2]) {
#pragma unroll
        for (int ptt = 0; ptt < 2; ++ptt)
#pragma unroll
            for (int d = 0; d < 4; ++d) {
                const f32x4 bv = *(const f32x4*)&bp[(nb + d) * 16 + 4 * g];
                float s0 = hw_sin(fmaf((float)A[ptt][d][0], INVH, bv[0]));
                float s1 = hw_sin(fmaf((float)A[ptt][d][1], INVH, bv[1]));
                float s2 = hw_sin(fmaf((float)A[ptt][d][2], INVH, bv[2]));
                float s3 = hw_sin(fmaf((float)A[ptt][d][3], INVH, bv[3]));
                Sa[ptt][d] = hi_bytes(pknorm(s0, s1), pknorm(s2, s3));
                const f32x4 bw = *(const f32x4*)&bp[(nb + 4 + d) * 16 + 4 * g];
                s0 = hw_sin(fmaf((float)A[ptt][4 + d][0], INVH, bw[0]));
                s1 = hw_sin(fmaf((float)A[ptt][4 + d][1], INVH, bw[1]));
                s2 = hw_sin(fmaf((float)A[ptt][4 + d][2], INVH, bw[2]));
                s3 = hw_sin(fmaf((float)A[ptt][4 + d][3], INVH, bw[3]));
                Sb[ptt][d] = hi_bytes(pknorm(s0, s1), pknorm(s2, s3));
            }
    };
    // consume 4 frags (one k-step x 4 tiles, acc tiles tb..tb+3); refill quad
    auto quad_mfma = [&](const i32x4 (&S)[2], i32x4 (&A)[2][8], int tb,
                         int nslot, int nbase) {
        __builtin_amdgcn_s_setprio(1);
#pragma unroll
        for (int q = 0; q < 4; ++q) {
            A[0][tb + q] = MFI8(wreg[q], S[0], A[0][tb + q]);
            A[1][tb + q] = MFI8(wreg[q], S[1], A[1][tb + q]);
            wreg[q] = frag_i8(nslot, nbase + q);
        }
        __builtin_amdgcn_s_setprio(0);
    };

    initf(acc0A, 0);
    initf(acc0B, 8);
    __syncthreads();                    // chunks 0,1,2 staged & landed

    // ---- L0 (chunk 0, fp8 K=32): tiles 0..7 -> acc0A, 8..15 -> acc0B ----
    __builtin_amdgcn_s_setprio(1);
#pragma unroll
    for (int ntl = 0; ntl < 8; ++ntl) {
        const long long wl = frag_f8(ntl);
        const long long wh = frag_f8(8 + ntl);
#pragma unroll
        for (int ptt = 0; ptt < 2; ++ptt) {
            acc0A[ptt][ntl] = MF8(wl, af0[ptt], acc0A[ptt][ntl]);
            acc0B[ptt][ntl] = MF8(wh, af0[ptt], acc0B[ptt][ntl]);
        }
    }
    __builtin_amdgcn_s_setprio(0);
    // preload chunk1 frags 0..3 (slot 1)
#pragma unroll
    for (int i = 0; i < 4; ++i) wreg[i] = frag_i8(1, i);
    __syncthreads(); stage(3);

    // one chunk CK: frags 0-7 = k-step ss0 (SA), 8-15 = ss1 (SB); 4 quads,
    // last quad refills next chunk's frags 0..3 (slot valid pre-barrier).
#define PH(SA, SB, ACC, CK)                                            \
        quad_mfma(SA, ACC, 0, (CK) % 3, 4);                            \
        quad_mfma(SA, ACC, 4, (CK) % 3, 8);                            \
        quad_mfma(SB, ACC, 0, (CK) % 3, 12);                           \
        quad_mfma(SB, ACC, 4, ((CK) + 1) % 3, 0);                      \
        __syncthreads(); stage((CK) + 3);

#define LAYERX(C, PACKA, PACKB)                                        \
    do {                                                               \
        PACKA; zeroacc(accA);                                          \
        PH(S0, S1, accA, (C))                                          \
        PACKB; zeroacc(accB);                                          \
        PH(S0, S1, accB, (C) + 1)                                      \
        PH(S2, S3, accA, (C) + 2)                                      \
        PH(S2, S3, accB, (C) + 3)                                      \
    } while (0)

    LAYERX(1, packL0(acc0A, S0, S1), packL0(acc0B, S2, S3));                       // W1
    LAYERX(5, packH(accA, sb + 256, 0, S0, S1), packH(accB, sb + 256, 8, S2, S3)); // W2
    LAYERX(9, packH(accA, sb + 512, 0, S0, S1), packH(accB, sb + 512, 8, S2, S3)); // W3
    // last quad preloaded chunk13 frags 0..3 (= Wf k-steps 0..3)

    // ---- final: Wf int8 (wreg[0..3] = k-steps 0..3) ----
    packH(accA, sb + 768, 0, S0, S1);
    packH(accB, sb + 768, 8, S2, S3);
    {
        i32x4 fo[2];
        const i32x4 z = {0, 0, 0, 0};
        fo[0] = z; fo[1] = z;
#pragma unroll
        for (int ptt = 0; ptt < 2; ++ptt) {
            fo[ptt] = MFI8(wreg[0], S0[ptt], fo[ptt]);
            fo[ptt] = MFI8(wreg[1], S1[ptt], fo[ptt]);
            fo[ptt] = MFI8(wreg[2], S2[ptt], fo[ptt]);
            fo[ptt] = MFI8(wreg[3], S3[ptt], fo[ptt]);
        }
        if (g == 0) {
#pragma unroll
            for (int ptt = 0; ptt < 2; ++ptt) {
                const long long oi = base + w * 32 + ptt * 16 + p16;
                if (oi < total) {
                    float4 o;
                    o.x = fast_sigmoid((float)fo[ptt][0] * INVF + bfin[0]);
                    o.y = fast_sigmoid((float)fo[ptt][1] * INVF + bfin[1]);
                    o.z = fast_sigmoid((float)fo[ptt][2] * INVF + bfin[2]);
                    o.w = (float)fo[ptt][3] * INVF + bfin[3];
                    *(float4*)(out + oi * 4) = o;
                }
            }
        }
    }
}

extern "C" void kernel_launch(void* const* d_in, const int* in_sizes, int n_in,
                              void* d_out, int out_size, void* d_ws, size_t ws_size,
                              hipStream_t stream) {
    const float* points = (const float*)d_in[0];
    const float* vol    = (const float*)d_in[1];
    const float* W0 = (const float*)d_in[2];
    const float* b0 = (const float*)d_in[3];
    const float* W1 = (const float*)d_in[4];
    const float* b1 = (const float*)d_in[5];
    const float* W2 = (const float*)d_in[6];
    const float* b2 = (const float*)d_in[7];
    const float* W3 = (const float*)d_in[8];
    const float* b3 = (const float*)d_in[9];
    const float* Wf = (const float*)d_in[10];
    const float* bf = (const float*)d_in[11];

    const int B = in_sizes[1] / (32 * 32 * 32 * 32);
    const int N = in_sizes[0] / (3 * B);
    const long long total = (long long)B * N;
    const int tiles = (int)((total + 127) / 128);

    unsigned char* Wstream = (unsigned char*)d_ws;
    float* sb = (float*)((char*)d_ws + STREAM_BYTES);
    build_frags<<<(STREAM_BYTES / 8 + 255) / 256, 256, 0, stream>>>(
        W0, W1, W2, W3, Wf, Wstream);
    scale_biases<<<4, 256, 0, stream>>>(b0, b1, b2, b3, sb);

    const size_t fixed = (size_t)STREAM_BYTES + SBIAS_BYTES;
    const int use_cl = (ws_size >= fixed + (size_t)B * 32768 * 32 * 4) ? 1 : 0;
    float* volcl = (float*)((char*)d_ws + fixed);
    if (use_cl) {
        const int nvox = B * 32768;
        vol_chlast<<<(nvox + 255) / 256, 256, 0, stream>>>(vol, volcl, nvox);
    }

    siren_pl<<<tiles, THREADS, 0, stream>>>(
        points, vol, bf, Wstream, sb, volcl, use_cl,
        (float*)d_out, total, N);
}

// Round 22
// 90.677 us; speedup vs baseline: 1.6814x; 1.6814x over previous
//
#include <hip/hip_runtime.h>
#include <math.h>

#define THREADS 256   // 4 waves/block, 32 pts/wave, 128 pts/block

typedef __attribute__((ext_vector_type(4))) float f32x4;
typedef __attribute__((ext_vector_type(4))) int   i32x4;

#define INV2PI 0.15915494309189535f
#define WS     512.0f            // L0 fp8 weight pre-scale (2^9)
#define INV_WS 0.001953125f      // 2^-9
#define SW     61440.0f          // hidden int8 weight scale (|q| <= ~125)
#define SWF    8192.0f           // Wf int8 weight scale
#define QA     127.99609375f     // activation scale = 32767/256 (pknorm hi-byte)
#define INVH   (1.0f / (SW * QA))
#define INVF   (1.0f / (SWF * QA))

// ---------------------------------------------------------------------------
// Stream: 14 chunks x 16KB = 224KB.
//   chunk 0      : L0 fp8 (W0 256x32, xWS/2pi): 16 frags x 512B (K=32 layout:
//                  lane l: row=f*16+(l&15), k=8*(l>>4)+i) + 8KB zero
//   chunks 1..12 : W1..W3 int8, 4 chunks/layer, cc: 0=(t0-7,s0-1) 1=(t8-15,s0-1)
//                  2=(t0-7,s2-3) 3=(t8-15,s2-3). Frag = 1KB = tile(16n) x 64k.
//                  within chunk: idx = ss*8 + tl. Lane l: n=tile*16+(l&15),
//                  k_local = 16*(l>>4)+i (i 0..15), col = sigma64(64*step+k_local).
//   chunk 13     : Wf int8: frags 0..3 = k-steps 0..3 (rows>=4 zero), rest zero.
// sigma64: swap k bit-fields [5:4] (g) and [3:2] (dword) — involution.
// Occupancy axis closed: 1 wave/SIMD=142us(r8), 2=90.7us(r18/r20, THIS),
// 3=spill 152us(r21, 84-VGPR cap), 4=spill 581us(r9, 64-VGPR cap).
#define NCHUNK 14
#define STREAM_BYTES (NCHUNK * 16384)
#define SBIAS_BYTES 4096

__device__ __host__ __forceinline__ int sigma64(int k) {
    return (k & 0xC3) | ((k & 0x30) >> 2) | ((k & 0x0C) << 2);
}

__device__ __forceinline__ float fast_sigmoid(float x) {
    return 1.0f / (1.0f + __expf(-x));
}

// hardware sin, input in REVOLUTIONS (weights/biases pre-scaled by 1/2pi)
__device__ __forceinline__ float hw_sin(float x) {
    float r;
    asm("v_sin_f32 %0, %1" : "=v"(r) : "v"(x));
    return r;
}

// fp8 e4m3 packing (OCP on gfx950) — L0 path only
__device__ __forceinline__ unsigned pk8_lo(float a, float b) {
    return (unsigned)__builtin_amdgcn_cvt_pk_fp8_f32(a, b, 0, false);
}
__device__ __forceinline__ unsigned pk8_hi(unsigned old, float a, float b) {
    return (unsigned)__builtin_amdgcn_cvt_pk_fp8_f32(a, b, (int)old, true);
}

// int8 activation packing: pknorm (x*32767 clamp) then take high bytes
__device__ __forceinline__ unsigned pknorm(float a, float b) {
    unsigned d;
    asm("v_cvt_pknorm_i16_f32 %0, %1, %2" : "=v"(d) : "v"(a), "v"(b));
    return d;
}
__device__ __forceinline__ int hi_bytes(unsigned lo, unsigned hi) {
    // dst = [lo.b1, lo.b3, hi.b1, hi.b3]
    return (int)__builtin_amdgcn_perm(hi, lo, 0x07050301u);
}

// ---------------- prep kernels ----------------
__device__ __forceinline__ signed char q8(float x) {
    const float c = fminf(fmaxf(x, -127.0f), 127.0f);
    return (signed char)(int)rintf(c);
}

__global__ void build_frags(const float* __restrict__ W0,
                            const float* __restrict__ W1,
                            const float* __restrict__ W2,
                            const float* __restrict__ W3,
                            const float* __restrict__ Wf,
                            unsigned char* __restrict__ stream) {
    const int gid = blockIdx.x * 256 + threadIdx.x;   // 0 .. 28671 (8B slices)
    if (gid >= STREAM_BYTES / 8) return;
    const int off = gid * 8;
    const int c = off >> 14;
    const int wi = off & 16383;
    unsigned char* dst = stream + off;
    unsigned char b[8];
#pragma unroll
    for (int i = 0; i < 8; ++i) b[i] = 0;

    if (c == 0) {
        if (wi < 8192) {                 // L0 fp8, K=32 layout
            const int f = wi >> 9;
            const int wf = wi & 511;
            const int l = wf >> 3;
            const int p16 = l & 15, g = l >> 4;
            const float* row = W0 + (size_t)(f * 16 + p16) * 32;
            float v[8];
#pragma unroll
            for (int i = 0; i < 8; ++i) v[i] = row[8 * g + i] * (INV2PI * WS);
            unsigned u0 = pk8_hi(pk8_lo(v[0], v[1]), v[2], v[3]);
            unsigned u1 = pk8_hi(pk8_lo(v[4], v[5]), v[6], v[7]);
#pragma unroll
            for (int i = 0; i < 4; ++i) { b[i] = (u0 >> (8 * i)) & 0xFF; b[4 + i] = (u1 >> (8 * i)) & 0xFF; }
        }
    } else if (c <= 12) {                // hidden int8
        const int t0 = c - 1;
        const int h = t0 >> 2;           // 0,1,2 -> W1,W2,W3
        const int cc = t0 & 3;
        const int tb = (cc & 1) * 8;
        const int sbase = (cc >> 1) * 2;
        const int fragidx = wi >> 10;    // 0..15
        const int wf = wi & 1023;
        const int l = wf >> 4;
        const int ib = wf & 15;          // 0 or 8
        const int ss = fragidx >> 3, tl = fragidx & 7;
        const int n = (tb + tl) * 16 + (l & 15);
        const float* W = (h == 0) ? W1 : (h == 1) ? W2 : W3;
        const float* row = W + (size_t)n * 256;
#pragma unroll
        for (int i = 0; i < 8; ++i) {
            const int k = 64 * (sbase + ss) + 16 * (l >> 4) + ib + i;
            b[i] = (unsigned char)q8(row[sigma64(k)] * (INV2PI * SW));
        }
    } else {                             // chunk 13: Wf int8
        const int fragidx = wi >> 10;
        const int wf = wi & 1023;
        const int l = wf >> 4;
        const int ib = wf & 15;
        const int r = l & 15;
        if (fragidx < 4 && r < 4) {
            const int s = fragidx;
            const float* row = Wf + (size_t)r * 256;
#pragma unroll
            for (int i = 0; i < 8; ++i) {
                const int k = 64 * s + 16 * (l >> 4) + ib + i;
                b[i] = (unsigned char)q8(row[sigma64(k)] * SWF);
            }
        }
    }
    unsigned long long pk = 0;
#pragma unroll
    for (int i = 0; i < 8; ++i) pk |= (unsigned long long)b[i] << (8 * i);
    *(unsigned long long*)dst = pk;
}

__global__ void scale_biases(const float* __restrict__ b0, const float* __restrict__ b1,
                             const float* __restrict__ b2, const float* __restrict__ b3,
                             float* __restrict__ sb) {
    const int i = blockIdx.x * 256 + threadIdx.x;   // 0..1023
    const int l = i >> 8, j = i & 255;
    if (l == 0)      sb[i] = b0[j] * (INV2PI * WS);   // L0 f32-acc init
    else if (l == 1) sb[i] = b1[j] * INV2PI;          // fma-folded biases
    else if (l == 2) sb[i] = b2[j] * INV2PI;
    else             sb[i] = b3[j] * INV2PI;
}

// vol [B][32][32768] f32 -> dst [B*32768][32] f32 (channel-last)
__global__ void vol_chlast(const float* __restrict__ vol, float* __restrict__ dst, int nvox) {
    int v = blockIdx.x * 256 + threadIdx.x;
    if (v >= nvox) return;
    const int b = v >> 15, idx = v & 32767;
    const float* s = vol + (size_t)b * 32 * 32768 + idx;
    float* d = dst + (size_t)v * 32;
#pragma unroll
    for (int c = 0; c < 32; ++c) d[c] = s[(size_t)c * 32768];
}

// ---------------- main fused kernel ----------------
#define MF8(a, b, c)  __builtin_amdgcn_mfma_f32_16x16x32_fp8_fp8((a), (b), (c), 0, 0, 0)
#define MFI8(a, b, c) __builtin_amdgcn_mfma_i32_16x16x64_i8((a), (b), (c), 0, 0, 0)

__global__ __launch_bounds__(THREADS, 2)
void siren_pl(const float* __restrict__ points,
              const float* __restrict__ vol,
              const float* __restrict__ bfin,
              const unsigned char* __restrict__ Wstream,
              const float* __restrict__ sb,
              const float* __restrict__ volcl, int use_cl,
              float* __restrict__ out, long long total, int N) {
    __shared__ __align__(16) unsigned char ring[3 * 16384];   // 48KB -> 2 blocks/CU

    const int tid = (int)threadIdx.x;
    const int w = tid >> 6;
    const int lane = tid & 63;
    const int p16 = lane & 15;
    const int g = lane >> 4;

    const long long base = (long long)blockIdx.x * 128;

    auto stage = [&](int c) {
        if (c >= NCHUNK) return;
        const unsigned char* src = Wstream + (size_t)c * 16384;
        unsigned char* dstbase = ring + (c % 3) * 16384;
#pragma unroll
        for (int q = 0; q < 4; ++q) {
            const int off = (q * 4 + w) * 1024;
            __builtin_amdgcn_global_load_lds(
                (const __attribute__((address_space(1))) unsigned int*)(src + off + lane * 16),
                (__attribute__((address_space(3))) unsigned int*)(dstbase + off),
                16, 0, 0);
        }
    };
    stage(0);
    stage(1);
    stage(2);

    // ---- sample 2 points per lane: channels 8g..8g+7, pack to fp8 (L0) ----
    long long af0[2];
    {
#pragma unroll
        for (int ptt = 0; ptt < 2; ++ptt) {
            const long long gidx = base + w * 32 + ptt * 16 + p16;
            const long long gp = gidx < total ? gidx : total - 1;
            const int bi = (int)(gp / N);
            const float* pp = points + gp * 3;
            const float sc = 1.0f / 0.6f;
            const float ix = (pp[0] * sc + 1.0f) * 16.0f - 0.5f;
            const float iy = (pp[1] * sc + 1.0f) * 16.0f - 0.5f;
            const float iz = (pp[2] * sc + 1.0f) * 16.0f - 0.5f;
            const float fx = floorf(ix), fy = floorf(iy), fz = floorf(iz);
            const float wx = ix - fx, wy = iy - fy, wz = iz - fz;
            const int x0 = (int)fminf(fmaxf(fx, 0.0f), 31.0f);
            const int x1 = (int)fminf(fmaxf(fx + 1.0f, 0.0f), 31.0f);
            const int y0 = (int)fminf(fmaxf(fy, 0.0f), 31.0f);
            const int y1 = (int)fminf(fmaxf(fy + 1.0f, 0.0f), 31.0f);
            const int z0 = (int)fminf(fmaxf(fz, 0.0f), 31.0f);
            const int z1 = (int)fminf(fmaxf(fz + 1.0f, 0.0f), 31.0f);
            const int i000 = (z0 * 32 + y0) * 32 + x0, i001 = (z0 * 32 + y0) * 32 + x1;
            const int i010 = (z0 * 32 + y1) * 32 + x0, i011 = (z0 * 32 + y1) * 32 + x1;
            const int i100 = (z1 * 32 + y0) * 32 + x0, i101 = (z1 * 32 + y0) * 32 + x1;
            const int i110 = (z1 * 32 + y1) * 32 + x0, i111 = (z1 * 32 + y1) * 32 + x1;
            const float omx = 1.0f - wx, omy = 1.0f - wy, omz = 1.0f - wz;
            const float w000 = omz * omy * omx, w001 = omz * omy * wx;
            const float w010 = omz * wy * omx,  w011 = omz * wy * wx;
            const float w100 = wz * omy * omx,  w101 = wz * omy * wx;
            const float w110 = wz * wy * omx,   w111 = wz * wy * wx;

            f32x4 a[2];
            if (use_cl) {
                const float* vb = volcl + (size_t)bi * 32768 * 32 + g * 8;
#pragma unroll
                for (int h = 0; h < 2; ++h) {
                    const float* vh = vb + h * 4;
                    a[h]  = w000 * *(const f32x4*)(vh + (size_t)i000 * 32);
                    a[h] += w001 * *(const f32x4*)(vh + (size_t)i001 * 32);
                    a[h] += w010 * *(const f32x4*)(vh + (size_t)i010 * 32);
                    a[h] += w011 * *(const f32x4*)(vh + (size_t)i011 * 32);
                    a[h] += w100 * *(const f32x4*)(vh + (size_t)i100 * 32);
                    a[h] += w101 * *(const f32x4*)(vh + (size_t)i101 * 32);
                    a[h] += w110 * *(const f32x4*)(vh + (size_t)i110 * 32);
                    a[h] += w111 * *(const f32x4*)(vh + (size_t)i111 * 32);
                }
            } else {
                const float* vb = vol + ((size_t)bi * 32 + (size_t)g * 8) * 32768;
#pragma unroll
                for (int c = 0; c < 8; ++c) {
                    const float* vc = vb + (size_t)c * 32768;
                    a[c >> 2][c & 3] =
                        vc[i000] * w000 + vc[i001] * w001 + vc[i010] * w010 + vc[i011] * w011 +
                        vc[i100] * w100 + vc[i101] * w101 + vc[i110] * w110 + vc[i111] * w111;
                }
            }
            const unsigned u0 = pk8_hi(pk8_lo(a[0][0], a[0][1]), a[0][2], a[0][3]);
            const unsigned u1 = pk8_hi(pk8_lo(a[1][0], a[1][1]), a[1][2], a[1][3]);
            af0[ptt] = (long long)(((unsigned long long)u1 << 32) | u0);
        }
    }

    f32x4 acc0A[2][8], acc0B[2][8];   // L0 f32 acc (dies after first pack)
    i32x4 accA[2][8],  accB[2][8];    // hidden int32 acc
    i32x4 S0[2], S1[2], S2[2], S3[2]; // packed int8 activations, k-steps 0..3
    i32x4 wreg[8];                    // rotating weight A-frag buffer (16B/lane)

    auto frag_i8 = [&](int slot, int idx) -> i32x4 {
        return *(const i32x4*)&ring[slot * 16384 + idx * 1024 + lane * 16];
    };
    auto frag_f8 = [&](int idx) -> long long {      // L0 frags, slot 0
        return *(const long long*)&ring[idx * 512 + lane * 8];
    };
    auto initf = [&](f32x4 (&A)[2][8], int ntbase) {
#pragma unroll
        for (int m = 0; m < 8; ++m) {
            const f32x4 bv = *(const f32x4*)&sb[(ntbase + m) * 16 + 4 * g];
            A[0][m] = bv; A[1][m] = bv;
        }
    };
    auto zeroacc = [&](i32x4 (&A)[2][8]) {
        const i32x4 z = {0, 0, 0, 0};
#pragma unroll
        for (int m = 0; m < 8; ++m) { A[0][m] = z; A[1][m] = z; }
    };
    // L0 pack: f32 acc (bias pre-added, xWS/2pi) -> sin -> int8 hi-bytes
    auto packL0 = [&](f32x4 (&A)[2][8], i32x4 (&Sa)[2], i32x4 (&Sb)[2]) {
#pragma unroll
        for (int ptt = 0; ptt < 2; ++ptt)
#pragma unroll
            for (int d = 0; d < 4; ++d) {
                float s0 = hw_sin(A[ptt][d][0] * INV_WS);
                float s1 = hw_sin(A[ptt][d][1] * INV_WS);
                float s2 = hw_sin(A[ptt][d][2] * INV_WS);
                float s3 = hw_sin(A[ptt][d][3] * INV_WS);
                Sa[ptt][d] = hi_bytes(pknorm(s0, s1), pknorm(s2, s3));
                s0 = hw_sin(A[ptt][4 + d][0] * INV_WS);
                s1 = hw_sin(A[ptt][4 + d][1] * INV_WS);
                s2 = hw_sin(A[ptt][4 + d][2] * INV_WS);
                s3 = hw_sin(A[ptt][4 + d][3] * INV_WS);
                Sb[ptt][d] = hi_bytes(pknorm(s0, s1), pknorm(s2, s3));
            }
    };
    // hidden pack: i32 acc -> fma(dequant + bias) -> sin -> int8 hi-bytes
    auto packH = [&](i32x4 (&A)[2][8], const float* bp, int nb,
                     i32x4 (&Sa)[2], i32x4 (&Sb)[2]) {
#pragma unroll
        for (int ptt = 0; ptt < 2; ++ptt)
#pragma unroll
            for (int d = 0; d < 4; ++d) {
                const f32x4 bv = *(const f32x4*)&bp[(nb + d) * 16 + 4 * g];
                float s0 = hw_sin(fmaf((float)A[ptt][d][0], INVH, bv[0]));
                float s1 = hw_sin(fmaf((float)A[ptt][d][1], INVH, bv[1]));
                float s2 = hw_sin(fmaf((float)A[ptt][d][2], INVH, bv[2]));
                float s3 = hw_sin(fmaf((float)A[ptt][d][3], INVH, bv[3]));
                Sa[ptt][d] = hi_bytes(pknorm(s0, s1), pknorm(s2, s3));
                const f32x4 bw = *(const f32x4*)&bp[(nb + 4 + d) * 16 + 4 * g];
                s0 = hw_sin(fmaf((float)A[ptt][4 + d][0], INVH, bw[0]));
                s1 = hw_sin(fmaf((float)A[ptt][4 + d][1], INVH, bw[1]));
                s2 = hw_sin(fmaf((float)A[ptt][4 + d][2], INVH, bw[2]));
                s3 = hw_sin(fmaf((float)A[ptt][4 + d][3], INVH, bw[3]));
                Sb[ptt][d] = hi_bytes(pknorm(s0, s1), pknorm(s2, s3));
            }
    };
    // consume 8 frags (one k-step x 8 tiles) from wreg; rotate-refill
    auto half_mfma = [&](const i32x4 (&S)[2], i32x4 (&A)[2][8], int nslot, int nbase) {
        __builtin_amdgcn_s_setprio(1);
#pragma unroll
        for (int tl = 0; tl < 8; ++tl) {
            A[0][tl] = MFI8(wreg[tl], S[0], A[0][tl]);
            A[1][tl] = MFI8(wreg[tl], S[1], A[1][tl]);
            wreg[tl] = frag_i8(nslot, nbase + tl);
        }
        __builtin_amdgcn_s_setprio(0);
    };

    initf(acc0A, 0);
    initf(acc0B, 8);
    __syncthreads();                    // chunks 0,1,2 staged & landed

    // ---- L0 (chunk 0, fp8 K=32): tiles 0..7 -> acc0A, 8..15 -> acc0B ----
    __builtin_amdgcn_s_setprio(1);
#pragma unroll
    for (int ntl = 0; ntl < 8; ++ntl) {
        const long long wl = frag_f8(ntl);
        const long long wh = frag_f8(8 + ntl);
#pragma unroll
        for (int ptt = 0; ptt < 2; ++ptt) {
            acc0A[ptt][ntl] = MF8(wl, af0[ptt], acc0A[ptt][ntl]);
            acc0B[ptt][ntl] = MF8(wh, af0[ptt], acc0B[ptt][ntl]);
        }
    }
    __builtin_amdgcn_s_setprio(0);
    // preload chunk1 frags 0..7 (slot 1)
#pragma unroll
    for (int i = 0; i < 8; ++i) wreg[i] = frag_i8(1, i);
    __syncthreads(); stage(3);

#define PH(SA, SB, ACC, CK)                                            \
        half_mfma(SA, ACC, (CK) % 3, 8);                               \
        half_mfma(SB, ACC, ((CK) + 1) % 3, 0);                         \
        __syncthreads(); stage((CK) + 3);

#define LAYERX(C, PACKA, PACKB)                                        \
    do {                                                               \
        PACKA; zeroacc(accA);                                          \
        PH(S0, S1, accA, (C))                                          \
        PACKB; zeroacc(accB);                                          \
        PH(S0, S1, accB, (C) + 1)                                      \
        PH(S2, S3, accA, (C) + 2)                                      \
        PH(S2, S3, accB, (C) + 3)                                      \
    } while (0)

    LAYERX(1, packL0(acc0A, S0, S1), packL0(acc0B, S2, S3));                       // W1
    LAYERX(5, packH(accA, sb + 256, 0, S0, S1), packH(accB, sb + 256, 8, S2, S3)); // W2
    LAYERX(9, packH(accA, sb + 512, 0, S0, S1), packH(accB, sb + 512, 8, S2, S3)); // W3
    // last PH preloaded chunk13 frags 0..7 (Wf steps 0..3 + zero pad)

    // ---- final: Wf int8 (wreg[0..3] = k-steps 0..3) ----
    packH(accA, sb + 768, 0, S0, S1);
    packH(accB, sb + 768, 8, S2, S3);
    {
        i32x4 fo[2];
        const i32x4 z = {0, 0, 0, 0};
        fo[0] = z; fo[1] = z;
#pragma unroll
        for (int ptt = 0; ptt < 2; ++ptt) {
            fo[ptt] = MFI8(wreg[0], S0[ptt], fo[ptt]);
            fo[ptt] = MFI8(wreg[1], S1[ptt], fo[ptt]);
            fo[ptt] = MFI8(wreg[2], S2[ptt], fo[ptt]);
            fo[ptt] = MFI8(wreg[3], S3[ptt], fo[ptt]);
        }
        if (g == 0) {
#pragma unroll
            for (int ptt = 0; ptt < 2; ++ptt) {
                const long long oi = base + w * 32 + ptt * 16 + p16;
                if (oi < total) {
                    float4 o;
                    o.x = fast_sigmoid((float)fo[ptt][0] * INVF + bfin[0]);
                    o.y = fast_sigmoid((float)fo[ptt][1] * INVF + bfin[1]);
                    o.z = fast_sigmoid((float)fo[ptt][2] * INVF + bfin[2]);
                    o.w = (float)fo[ptt][3] * INVF + bfin[3];
                    *(float4*)(out + oi * 4) = o;
                }
            }
        }
    }
}

extern "C" void kernel_launch(void* const* d_in, const int* in_sizes, int n_in,
                              void* d_out, int out_size, void* d_ws, size_t ws_size,
                              hipStream_t stream) {
    const float* points = (const float*)d_in[0];
    const float* vol    = (const float*)d_in[1];
    const float* W0 = (const float*)d_in[2];
    const float* b0 = (const float*)d_in[3];
    const float* W1 = (const float*)d_in[4];
    const float* b1 = (const float*)d_in[5];
    const float* W2 = (const float*)d_in[6];
    const float* b2 = (const float*)d_in[7];
    const float* W3 = (const float*)d_in[8];
    const float* b3 = (const float*)d_in[9];
    const float* Wf = (const float*)d_in[10];
    const float* bf = (const float*)d_in[11];

    const int B = in_sizes[1] / (32 * 32 * 32 * 32);
    const int N = in_sizes[0] / (3 * B);
    const long long total = (long long)B * N;
    const int tiles = (int)((total + 127) / 128);

    unsigned char* Wstream = (unsigned char*)d_ws;
    float* sb = (float*)((char*)d_ws + STREAM_BYTES);
    build_frags<<<(STREAM_BYTES / 8 + 255) / 256, 256, 0, stream>>>(
        W0, W1, W2, W3, Wf, Wstream);
    scale_biases<<<4, 256, 0, stream>>>(b0, b1, b2, b3, sb);

    const size_t fixed = (size_t)STREAM_BYTES + SBIAS_BYTES;
    const int use_cl = (ws_size >= fixed + (size_t)B * 32768 * 32 * 4) ? 1 : 0;
    float* volcl = (float*)((char*)d_ws + fixed);
    if (use_cl) {
        const int nvox = B * 32768;
        vol_chlast<<<(nvox + 255) / 256, 256, 0, stream>>>(vol, volcl, nvox);
    }

    siren_pl<<<tiles, THREADS, 0, stream>>>(
        points, vol, bf, Wstream, sb, volcl, use_cl,
        (float*)d_out, total, N);
}